// Round 12
// baseline (150.705 us; speedup 1.0000x reference)
//
#include <hip/hip_runtime.h>
#include <hip/hip_bf16.h>
#include <cstddef>
#include <cstdint>

#define Nn 12288
#define MSTRIDE 260        // ints per mask row in LDS; 260%32=4 -> 2-way banks (free)
#define DSTOFF (2 * 16 * MSTRIDE)   // int offset of dst slots in lm
#define LOG2E 1.44269504088896340736f

typedef __bf16 bf16x8 __attribute__((ext_vector_type(8)));
typedef float  f32x4  __attribute__((ext_vector_type(4)));
typedef int    i32x4  __attribute__((ext_vector_type(4)));

__device__ __forceinline__ void gload_lds16_nt(const void* g, void* l) {
    __builtin_amdgcn_global_load_lds(
        (const __attribute__((address_space(1))) void*)g,
        (__attribute__((address_space(3))) void*)l, 16, 0, 2 /*nt (A/B-verified)*/);
}
__device__ __forceinline__ void gload_lds4(const void* g, void* l) {
    __builtin_amdgcn_global_load_lds(
        (const __attribute__((address_space(1))) void*)g,
        (__attribute__((address_space(3))) void*)l, 4, 0, 0);
}

// ---------------------------------------------------------------------------
// Kernel 1 (verified, unchanged): wh = x @ W; whB in MFMA-fragment order;
// src/dst prescaled by log2(e) for native exp2.
// ---------------------------------------------------------------------------
__global__ __launch_bounds__(256) void prep_kernel(
    const float* __restrict__ x, const float* __restrict__ W,
    const float* __restrict__ wa, __bf16* __restrict__ whB,
    float* __restrict__ src, float* __restrict__ dst)
{
    __shared__ float  Wl[64 * 64];
    __shared__ float  Xl[64 * 64];
    __shared__ __bf16 whl[64 * 72];
    int t = threadIdx.x;
    int R0 = blockIdx.x * 64;
    for (int i = t; i < 4096; i += 256) {
        Wl[i] = W[i];
        Xl[i] = x[(size_t)R0 * 64 + i];
    }
    __syncthreads();
    int c   = t & 63;
    int r16 = (t >> 6) * 16;
    float vals[16];
    #pragma unroll
    for (int k = 0; k < 16; ++k) vals[k] = 0.f;
    #pragma unroll 16
    for (int kk = 0; kk < 64; ++kk) {
        float wv = Wl[kk * 64 + c];
        #pragma unroll
        for (int k = 0; k < 16; ++k)
            vals[k] = fmaf(Xl[(r16 + k) * 64 + kk], wv, vals[k]);
    }
    #pragma unroll
    for (int k = 0; k < 16; ++k) whl[c * 72 + r16 + k] = (__bf16)vals[k];
    __syncthreads();
    if (t < 64) {
        float s = 0.f, d = 0.f;
        #pragma unroll 16
        for (int cc = 0; cc < 64; ++cc) {
            float v = (float)whl[cc * 72 + t];
            s = fmaf(v, wa[cc], s);
            d = fmaf(v, wa[64 + cc], d);
        }
        src[R0 + t] = s * LOG2E;
        dst[R0 + t] = d * LOG2E;
    }
    #pragma unroll
    for (int gg = 0; gg < 2; ++gg) {
        int gidx   = t * 2 + gg;
        int jc_loc = gidx >> 8;
        int q      = (gidx >> 6) & 3;
        int lane   = gidx & 63;
        int crow   = (lane & 15) + 16 * q;
        int jrow   = jc_loc * 32 + (lane >> 4) * 8;
        bf16x8 v = *(const bf16x8*)&whl[crow * 72 + jrow];
        int jc = blockIdx.x * 2 + jc_loc;
        *(bf16x8*)&whB[((size_t)(jc * 4 + q) * 64 + lane) * 8] = v;
    }
}

// ---------------------------------------------------------------------------
// Kernel 2: EXACT R5 body (141.8 us verified), j-segmented. Block =
// 16 rows x SEGJ cols; NSEG=2 -> grid 1536 (even block rounds per CU).
// whB seg arithmetic FIXED vs R10: chunk = seg*(SEGJ/32) + TT*8 + wid*2.
// ---------------------------------------------------------------------------
template <int NSEG>
__global__ __launch_bounds__(256) void attn_kernel(
    const int* __restrict__ mask, const __bf16* __restrict__ whB,
    const float* __restrict__ src, const float* __restrict__ dstv,
    float* __restrict__ pnum, float* __restrict__ pz)
{
    constexpr int SEGJ = Nn / NSEG;
    constexpr int NT   = SEGJ / 256;
    __shared__ int lm[DSTOFF + 2 * 256];   // mask dbuf [2][16][260] + dst dbuf

    int t    = threadIdx.x;
    int lane = t & 63;
    int wid  = t >> 6;
    int seg  = blockIdx.x / (Nn / 16);
    int g    = blockIdx.x % (Nn / 16);
    int row  = lane & 15;
    int kg   = lane >> 4;
    int jl   = kg * 8;

    float srow = src[g * 16 + row];
    asm volatile("" :: "v"(srow));   // resolve before pipeline starts

    bf16x8 vones;
    #pragma unroll
    for (int e = 0; e < 8; ++e) vones[e] = (__bf16)1.0f;

    i32x4 bset[2][8];
    f32x4 acc0 = {0.f, 0.f, 0.f, 0.f}, acc1 = acc0, acc2 = acc0, acc3 = acc0;
    f32x4 accZ = acc0;

#define STAGE(B, TT)                                                          \
    do {                                                                      \
        _Pragma("unroll")                                                     \
        for (int rr = 0; rr < 4; ++rr) {                                      \
            int rs = wid * 4 + rr;                                            \
            gload_lds16_nt(mask + (size_t)(g * 16 + rs) * Nn + seg * SEGJ +   \
                               (TT) * 256 + lane * 4,                         \
                           &lm[(B) * 4160 + rs * MSTRIDE]);                   \
        }                                                                     \
        gload_lds4(dstv + seg * SEGJ + (TT) * 256 + wid * 64 + lane,          \
                   &lm[DSTOFF + (B) * 256 + wid * 64]);                       \
    } while (0)

#define BLOAD(P, TT)                                                          \
    do {                                                                      \
        const char* _b0 = (const char*)whB +                                  \
                          ((size_t)(seg * (SEGJ / 32) + (TT) * 8 + wid * 2))  \
                              * 4096 +                                        \
                          (size_t)lane * 16;                                  \
        const char* _b1 = _b0 + 4096;                                         \
        asm volatile("global_load_dwordx4 %0, %1, off"                        \
                     : "=v"(bset[P][0]) : "v"(_b0));                          \
        asm volatile("global_load_dwordx4 %0, %1, off offset:1024"            \
                     : "=v"(bset[P][1]) : "v"(_b0));                          \
        asm volatile("global_load_dwordx4 %0, %1, off offset:2048"            \
                     : "=v"(bset[P][2]) : "v"(_b0));                          \
        asm volatile("global_load_dwordx4 %0, %1, off offset:3072"            \
                     : "=v"(bset[P][3]) : "v"(_b0));                          \
        asm volatile("global_load_dwordx4 %0, %1, off"                        \
                     : "=v"(bset[P][4]) : "v"(_b1));                          \
        asm volatile("global_load_dwordx4 %0, %1, off offset:1024"            \
                     : "=v"(bset[P][5]) : "v"(_b1));                          \
        asm volatile("global_load_dwordx4 %0, %1, off offset:2048"            \
                     : "=v"(bset[P][6]) : "v"(_b1));                          \
        asm volatile("global_load_dwordx4 %0, %1, off offset:3072"            \
                     : "=v"(bset[P][7]) : "v"(_b1));                          \
    } while (0)

#define COMPUTE(B, P)                                                         \
    do {                                                                      \
        const int*   mb = &lm[(B) * 4160 + row * MSTRIDE + wid * 64];         \
        const float* db = (const float*)&lm[DSTOFF + (B) * 256 + wid * 64];   \
        _Pragma("unroll")                                                     \
        for (int cc = 0; cc < 2; ++cc) {                                      \
            i32x4 m0 = *(const i32x4*)(mb + cc * 32 + jl);                    \
            i32x4 m1 = *(const i32x4*)(mb + cc * 32 + jl + 4);                \
            f32x4 d0 = *(const f32x4*)(db + cc * 32 + jl);                    \
            f32x4 d1 = *(const f32x4*)(db + cc * 32 + jl + 4);                \
            bf16x8 pa;                                                        \
            _Pragma("unroll")                                                 \
            for (int e = 0; e < 4; ++e) {                                     \
                float f0 = srow + d0[e];                                      \
                f0 = fmaxf(f0, 0.01f * f0);                                   \
                float w0 = __builtin_amdgcn_exp2f(f0);                        \
                w0 = (m0[e] > 0) ? w0 : 0.f;                                  \
                pa[e] = (__bf16)w0;                                           \
                float f1 = srow + d1[e];                                      \
                f1 = fmaxf(f1, 0.01f * f1);                                   \
                float w1 = __builtin_amdgcn_exp2f(f1);                        \
                w1 = (m1[e] > 0) ? w1 : 0.f;                                  \
                pa[4 + e] = (__bf16)w1;                                       \
            }                                                                 \
            acc0 = __builtin_amdgcn_mfma_f32_16x16x32_bf16(                   \
                pa, __builtin_bit_cast(bf16x8, bset[P][cc * 4 + 0]), acc0, 0, 0, 0); \
            acc1 = __builtin_amdgcn_mfma_f32_16x16x32_bf16(                   \
                pa, __builtin_bit_cast(bf16x8, bset[P][cc * 4 + 1]), acc1, 0, 0, 0); \
            acc2 = __builtin_amdgcn_mfma_f32_16x16x32_bf16(                   \
                pa, __builtin_bit_cast(bf16x8, bset[P][cc * 4 + 2]), acc2, 0, 0, 0); \
            acc3 = __builtin_amdgcn_mfma_f32_16x16x32_bf16(                   \
                pa, __builtin_bit_cast(bf16x8, bset[P][cc * 4 + 3]), acc3, 0, 0, 0); \
            accZ = __builtin_amdgcn_mfma_f32_16x16x32_bf16(                   \
                pa, vones, accZ, 0, 0, 0);                                    \
        }                                                                     \
    } while (0)

#define BODY_FULL(P)                                                          \
    do {                                                                      \
        STAGE((P) ^ 1, tt + 1);                                               \
        BLOAD((P) ^ 1, tt + 1);                                               \
        asm volatile("s_waitcnt vmcnt(13)" ::: "memory");                     \
        __builtin_amdgcn_sched_barrier(0);                                    \
        __builtin_amdgcn_s_barrier();                                         \
        __builtin_amdgcn_sched_barrier(0);                                    \
        COMPUTE(P, P);                                                        \
        __builtin_amdgcn_s_barrier();                                         \
        ++tt;                                                                 \
    } while (0)

    int tt = 0;
    STAGE(0, 0);      // prologue: tile 0 in flight
    BLOAD(0, 0);

    for (int it = 0; it < NT / 2 - 1; ++it) {   // tiles 0..NT-3
        BODY_FULL(0);
        BODY_FULL(1);
    }
    BODY_FULL(0);                       // tile NT-2 (stages NT-1 into buf 1)
    asm volatile("s_waitcnt vmcnt(0)" ::: "memory");
    __builtin_amdgcn_sched_barrier(0);
    __builtin_amdgcn_s_barrier();
    __builtin_amdgcn_sched_barrier(0);
    COMPUTE(1, 1);                      // tile NT-1

#undef BODY_FULL
#undef COMPUTE
#undef BLOAD
#undef STAGE

    // block reduce: 4 wave partials -> (16 x 64) tile + 16 z; write partials
    __syncthreads();
    float* red  = (float*)lm;          // [4][1024]
    float* redz = red + 4096;          // [4][16]
    #pragma unroll
    for (int r = 0; r < 4; ++r) {
        int orow = kg * 4 + r;         // C/D: row = 4*(lane>>4)+reg, col = lane&15
        red[wid * 1024 + orow * 64 + row]      = acc0[r];
        red[wid * 1024 + orow * 64 + row + 16] = acc1[r];
        red[wid * 1024 + orow * 64 + row + 32] = acc2[r];
        red[wid * 1024 + orow * 64 + row + 48] = acc3[r];
    }
    if (row == 0) {
        #pragma unroll
        for (int r = 0; r < 4; ++r) redz[wid * 16 + kg * 4 + r] = accZ[r];
    }
    __syncthreads();
    size_t pb = (size_t)blockIdx.x * 1024;
    #pragma unroll
    for (int k = 0; k < 4; ++k) {
        int idx = k * 256 + t;
        pnum[pb + idx] = red[idx] + red[1024 + idx] + red[2048 + idx] + red[3072 + idx];
    }
    if (t < 16)
        pz[(size_t)blockIdx.x * 16 + t] =
            redz[t] + redz[16 + t] + redz[32 + t] + redz[48 + t];
}

// ---------------------------------------------------------------------------
// Kernel 3: combine segment partials, normalize, add bias.
// Block (seg*(Nn/16)+g) holds rows g*16..+15.
// ---------------------------------------------------------------------------
__global__ __launch_bounds__(256) void finalize_kernel(
    const float* __restrict__ pnum, const float* __restrict__ pz,
    const float* __restrict__ bias, float* __restrict__ out, int nseg)
{
    int idx = blockIdx.x * 256 + threadIdx.x;
    int i = idx >> 6, c = idx & 63;
    int g = i >> 4, rl = i & 15;
    float num = 0.f, z = 0.f;
    for (int s = 0; s < nseg; ++s) {
        size_t b = (size_t)s * (Nn / 16) + g;
        num += pnum[b * 1024 + rl * 64 + c];
        z   += pz[b * 16 + rl];
    }
    z = (z != 0.f) ? z : 1.f;
    out[idx] = num / z + bias[c];
}

extern "C" void kernel_launch(void* const* d_in, const int* in_sizes, int n_in,
                              void* d_out, int out_size, void* d_ws, size_t ws_size,
                              hipStream_t stream) {
    const float* x    = (const float*)d_in[0];
    const int*   mask = (const int*)d_in[1];
    const float* W    = (const float*)d_in[2];
    const float* wa   = (const float*)d_in[3];
    const float* bias = (const float*)d_in[4];
    float* out = (float*)d_out;

    char* ws = (char*)d_ws;
    const size_t whB_bytes = (size_t)Nn * 64 * 2;   // 1.5 MB
    const size_t vec_bytes = (size_t)Nn * 4;        // 48 KB
    __bf16* whB = (__bf16*)ws;
    float*  src = (float*)(ws + whB_bytes);
    float*  dst = (float*)(ws + whB_bytes + vec_bytes);
    size_t fixed   = whB_bytes + 2 * vec_bytes;
    size_t per_seg = (size_t)(Nn / 16) * 1024 * 4 + (size_t)(Nn / 16) * 16 * 4;

    int nseg = 2;
    if (fixed + (size_t)nseg * per_seg > ws_size) nseg = 1;

    float* pnum = (float*)(ws + fixed);
    float* pz   = (float*)(ws + fixed + (size_t)nseg * (Nn / 16) * 1024 * 4);

    prep_kernel<<<Nn / 64, 256, 0, stream>>>(x, W, wa, whB, src, dst);

    int blocks = (Nn / 16) * nseg;
    if (nseg == 2) {
        attn_kernel<2><<<blocks, 256, 0, stream>>>(mask, whB, src, dst, pnum, pz);
    } else {
        attn_kernel<1><<<blocks, 256, 0, stream>>>(mask, whB, src, dst, pnum, pz);
    }

    finalize_kernel<<<(Nn * 64) / 256, 256, 0, stream>>>(pnum, pz, bias, out, nseg);
}

// Round 13
// 140.044 us; speedup vs baseline: 1.0761x; 1.0761x over previous
//
#include <hip/hip_runtime.h>
#include <hip/hip_bf16.h>
#include <cstddef>
#include <cstdint>

#define Nn 12288
#define LOG2E 1.44269504088896340736f
// LDS layout (ints): mask pair-bufs [2][16][516] = 16512 ; dst [2][256] at 16512
#define MROWI 516            // ints per mask row (2048 B + 16 pad)
#define MBUFI 8256           // ints per mask pair-buffer
#define DSTI  16512          // int offset of dst slots

typedef __bf16 bf16x8 __attribute__((ext_vector_type(8)));
typedef float  f32x4  __attribute__((ext_vector_type(4)));
typedef int    i32x4  __attribute__((ext_vector_type(4)));

__device__ __forceinline__ void gload_lds16_nt(const void* g, void* l) {
    __builtin_amdgcn_global_load_lds(
        (const __attribute__((address_space(1))) void*)g,
        (__attribute__((address_space(3))) void*)l, 16, 0, 2 /*nt*/);
}
__device__ __forceinline__ void gload_lds4(const void* g, void* l) {
    __builtin_amdgcn_global_load_lds(
        (const __attribute__((address_space(1))) void*)g,
        (__attribute__((address_space(3))) void*)l, 4, 0, 0);
}

// ---------------------------------------------------------------------------
// Kernel 1 (verified, unchanged): wh = x @ W; whB in MFMA-fragment order;
// src/dst prescaled by log2(e) for native exp2.
// ---------------------------------------------------------------------------
__global__ __launch_bounds__(256) void prep_kernel(
    const float* __restrict__ x, const float* __restrict__ W,
    const float* __restrict__ wa, __bf16* __restrict__ whB,
    float* __restrict__ src, float* __restrict__ dst)
{
    __shared__ float  Wl[64 * 64];
    __shared__ float  Xl[64 * 64];
    __shared__ __bf16 whl[64 * 72];
    int t = threadIdx.x;
    int R0 = blockIdx.x * 64;
    for (int i = t; i < 4096; i += 256) {
        Wl[i] = W[i];
        Xl[i] = x[(size_t)R0 * 64 + i];
    }
    __syncthreads();
    int c   = t & 63;
    int r16 = (t >> 6) * 16;
    float vals[16];
    #pragma unroll
    for (int k = 0; k < 16; ++k) vals[k] = 0.f;
    #pragma unroll 16
    for (int kk = 0; kk < 64; ++kk) {
        float wv = Wl[kk * 64 + c];
        #pragma unroll
        for (int k = 0; k < 16; ++k)
            vals[k] = fmaf(Xl[(r16 + k) * 64 + kk], wv, vals[k]);
    }
    #pragma unroll
    for (int k = 0; k < 16; ++k) whl[c * 72 + r16 + k] = (__bf16)vals[k];
    __syncthreads();
    if (t < 64) {
        float s = 0.f, d = 0.f;
        #pragma unroll 16
        for (int cc = 0; cc < 64; ++cc) {
            float v = (float)whl[cc * 72 + t];
            s = fmaf(v, wa[cc], s);
            d = fmaf(v, wa[64 + cc], d);
        }
        src[R0 + t] = s * LOG2E;
        dst[R0 + t] = d * LOG2E;
    }
    #pragma unroll
    for (int gg = 0; gg < 2; ++gg) {
        int gidx   = t * 2 + gg;
        int jc_loc = gidx >> 8;
        int q      = (gidx >> 6) & 3;
        int lane   = gidx & 63;
        int crow   = (lane & 15) + 16 * q;
        int jrow   = jc_loc * 32 + (lane >> 4) * 8;
        bf16x8 v = *(const bf16x8*)&whl[crow * 72 + jrow];
        int jc = blockIdx.x * 2 + jc_loc;
        *(bf16x8*)&whB[((size_t)(jc * 4 + q) * 64 + lane) * 8] = v;
    }
}

// ---------------------------------------------------------------------------
// Kernel 2: R5 compute/BLOAD byte-identical; mask staged per PAIR of bodies
// (16 rows x 2 KB, 8x 1-KB ops/wave, zero row-straddling -> 2x page locality).
// Ledger: even body issues 17 ops {8 B, 1 dst, 8 mask}, odd 9 {8 B, 1 dst};
// constant vmcnt(17) retires exactly the required group. Tail: 9, then 0.
// ---------------------------------------------------------------------------
__global__ __launch_bounds__(256) void attn_kernel(
    const int* __restrict__ mask, const __bf16* __restrict__ whB,
    const float* __restrict__ src, const float* __restrict__ dstv,
    const float* __restrict__ bias, float* __restrict__ out)
{
    __shared__ int lm[DSTI + 2 * 256];   // 68096 B

    int t    = threadIdx.x;
    int lane = t & 63;
    int wid  = t >> 6;
    int g    = blockIdx.x;
    int row  = lane & 15;
    int kg   = lane >> 4;
    int jl   = kg * 8;

    float srow = src[g * 16 + row];
    asm volatile("" :: "v"(srow));   // resolve before pipeline starts

    bf16x8 vones;
    #pragma unroll
    for (int e = 0; e < 8; ++e) vones[e] = (__bf16)1.0f;

    const char* mgb = (const char*)(mask + (size_t)g * 16 * Nn) + lane * 16;

    i32x4 bset[2][8];
    f32x4 acc0 = {0.f, 0.f, 0.f, 0.f}, acc1 = acc0, acc2 = acc0, acc3 = acc0;
    f32x4 accZ = acc0;

// stage mask for pair PR into buf SB: op k = wid*8+o covers row k>>1, half k&1
#define MSTAGE(SB, PR)                                                        \
    do {                                                                      \
        _Pragma("unroll")                                                     \
        for (int o = 0; o < 8; ++o) {                                         \
            int k    = wid * 8 + o;                                           \
            int rr   = k >> 1;                                                \
            int half = k & 1;                                                 \
            gload_lds16_nt(mgb + (size_t)rr * (Nn * 4) + (PR) * 2048 +        \
                               half * 1024,                                   \
                           (char*)lm + (SB) * (MBUFI * 4) + rr * (MROWI * 4) +\
                               half * 1024);                                  \
        }                                                                     \
    } while (0)

#define DSTAGE(PS, TT)                                                        \
    gload_lds4(dstv + (TT) * 256 + wid * 64 + lane,                           \
               (char*)lm + DSTI * 4 + (PS) * 1024 + wid * 256)

#define BLOAD(PS, TT)                                                         \
    do {                                                                      \
        const char* _b0 = (const char*)whB +                                  \
                          ((size_t)((TT) * 8 + wid * 2)) * 4096 +             \
                          (size_t)lane * 16;                                  \
        const char* _b1 = _b0 + 4096;                                         \
        asm volatile("global_load_dwordx4 %0, %1, off"                        \
                     : "=v"(bset[PS][0]) : "v"(_b0));                         \
        asm volatile("global_load_dwordx4 %0, %1, off offset:1024"            \
                     : "=v"(bset[PS][1]) : "v"(_b0));                         \
        asm volatile("global_load_dwordx4 %0, %1, off offset:2048"            \
                     : "=v"(bset[PS][2]) : "v"(_b0));                         \
        asm volatile("global_load_dwordx4 %0, %1, off offset:3072"            \
                     : "=v"(bset[PS][3]) : "v"(_b0));                         \
        asm volatile("global_load_dwordx4 %0, %1, off"                        \
                     : "=v"(bset[PS][4]) : "v"(_b1));                         \
        asm volatile("global_load_dwordx4 %0, %1, off offset:1024"            \
                     : "=v"(bset[PS][5]) : "v"(_b1));                         \
        asm volatile("global_load_dwordx4 %0, %1, off offset:2048"            \
                     : "=v"(bset[PS][6]) : "v"(_b1));                         \
        asm volatile("global_load_dwordx4 %0, %1, off offset:3072"            \
                     : "=v"(bset[PS][7]) : "v"(_b1));                         \
    } while (0)

#define COMPUTE(MB, H, PS)                                                    \
    do {                                                                      \
        const int*   mb = &lm[(MB) * MBUFI + row * MROWI + (H) * 256 +        \
                              wid * 64];                                      \
        const float* db = (const float*)&lm[DSTI + (PS) * 256 + wid * 64];    \
        _Pragma("unroll")                                                     \
        for (int cc = 0; cc < 2; ++cc) {                                      \
            i32x4 m0 = *(const i32x4*)(mb + cc * 32 + jl);                    \
            i32x4 m1 = *(const i32x4*)(mb + cc * 32 + jl + 4);                \
            f32x4 d0 = *(const f32x4*)(db + cc * 32 + jl);                    \
            f32x4 d1 = *(const f32x4*)(db + cc * 32 + jl + 4);                \
            bf16x8 pa;                                                        \
            _Pragma("unroll")                                                 \
            for (int e = 0; e < 4; ++e) {                                     \
                float f0 = srow + d0[e];                                      \
                f0 = fmaxf(f0, 0.01f * f0);                                   \
                float w0 = __builtin_amdgcn_exp2f(f0);                        \
                w0 = (m0[e] > 0) ? w0 : 0.f;                                  \
                pa[e] = (__bf16)w0;                                           \
                float f1 = srow + d1[e];                                      \
                f1 = fmaxf(f1, 0.01f * f1);                                   \
                float w1 = __builtin_amdgcn_exp2f(f1);                        \
                w1 = (m1[e] > 0) ? w1 : 0.f;                                  \
                pa[4 + e] = (__bf16)w1;                                       \
            }                                                                 \
            acc0 = __builtin_amdgcn_mfma_f32_16x16x32_bf16(                   \
                pa, __builtin_bit_cast(bf16x8, bset[PS][cc * 4 + 0]), acc0, 0, 0, 0); \
            acc1 = __builtin_amdgcn_mfma_f32_16x16x32_bf16(                   \
                pa, __builtin_bit_cast(bf16x8, bset[PS][cc * 4 + 1]), acc1, 0, 0, 0); \
            acc2 = __builtin_amdgcn_mfma_f32_16x16x32_bf16(                   \
                pa, __builtin_bit_cast(bf16x8, bset[PS][cc * 4 + 2]), acc2, 0, 0, 0); \
            acc3 = __builtin_amdgcn_mfma_f32_16x16x32_bf16(                   \
                pa, __builtin_bit_cast(bf16x8, bset[PS][cc * 4 + 3]), acc3, 0, 0, 0); \
            accZ = __builtin_amdgcn_mfma_f32_16x16x32_bf16(                   \
                pa, vones, accZ, 0, 0, 0);                                    \
        }                                                                     \
    } while (0)

#define WAITBAR(N)                                                            \
    do {                                                                      \
        asm volatile("s_waitcnt vmcnt(" #N ")" ::: "memory");                 \
        __builtin_amdgcn_sched_barrier(0);                                    \
        __builtin_amdgcn_s_barrier();                                         \
        __builtin_amdgcn_sched_barrier(0);                                    \
    } while (0)

// one pair = even body (stages next pair's mask) + odd body
#define PAIR_BODY(MB, SB)                                                     \
    do {                                                                      \
        BLOAD(1, tt + 1);                                                     \
        DSTAGE(1, tt + 1);                                                    \
        MSTAGE(SB, pr + 1);                                                   \
        WAITBAR(17);                                                          \
        COMPUTE(MB, 0, 0);                                                    \
        __builtin_amdgcn_s_barrier();                                         \
        ++tt;                                                                 \
        BLOAD(0, tt + 1);                                                     \
        DSTAGE(0, tt + 1);                                                    \
        WAITBAR(17);                                                          \
        COMPUTE(MB, 1, 1);                                                    \
        __builtin_amdgcn_s_barrier();                                         \
        ++tt;                                                                 \
        ++pr;                                                                 \
    } while (0)

    int tt = 0, pr = 0;
    // prologue: mask pair 0 -> buf 0, dst(0) -> slot 0, B(0) -> bset 0 (17 ops)
    MSTAGE(0, 0);
    DSTAGE(0, 0);
    BLOAD(0, 0);
    __builtin_amdgcn_sched_barrier(0);

    for (int it = 0; it < 11; ++it) {   // pairs 0..21
        PAIR_BODY(0, 1);
        PAIR_BODY(1, 0);
    }
    PAIR_BODY(0, 1);                    // pair 22 (stages pair 23 -> buf 1)

    // pair 23 (MB=1): even body 46
    BLOAD(1, tt + 1);
    DSTAGE(1, tt + 1);
    WAITBAR(9);
    COMPUTE(1, 0, 0);
    __builtin_amdgcn_s_barrier();
    // odd body 47
    WAITBAR(0);
    COMPUTE(1, 1, 1);

#undef PAIR_BODY
#undef WAITBAR
#undef COMPUTE
#undef BLOAD
#undef DSTAGE
#undef MSTAGE

    // block reduce: 4 wave partials -> (16 x 64) tile, normalize, + bias
    __syncthreads();
    float* red  = (float*)lm;          // [4][1024]
    float* redz = red + 4096;          // [4][16]
    #pragma unroll
    for (int r = 0; r < 4; ++r) {
        int orow = kg * 4 + r;         // C/D: row = 4*(lane>>4)+reg, col = lane&15
        red[wid * 1024 + orow * 64 + row]      = acc0[r];
        red[wid * 1024 + orow * 64 + row + 16] = acc1[r];
        red[wid * 1024 + orow * 64 + row + 32] = acc2[r];
        red[wid * 1024 + orow * 64 + row + 48] = acc3[r];
    }
    if (row == 0) {
        #pragma unroll
        for (int r = 0; r < 4; ++r) redz[wid * 16 + kg * 4 + r] = accZ[r];
    }
    __syncthreads();
    #pragma unroll
    for (int k = 0; k < 4; ++k) {
        int idx = k * 256 + t;
        int i   = idx >> 6;
        float sv = red[idx] + red[1024 + idx] + red[2048 + idx] + red[3072 + idx];
        float z  = redz[i] + redz[16 + i] + redz[32 + i] + redz[48 + i];
        z = (z != 0.f) ? z : 1.f;
        out[(size_t)g * 1024 + idx] = sv / z + bias[idx & 63];
    }
}

extern "C" void kernel_launch(void* const* d_in, const int* in_sizes, int n_in,
                              void* d_out, int out_size, void* d_ws, size_t ws_size,
                              hipStream_t stream) {
    const float* x    = (const float*)d_in[0];
    const int*   mask = (const int*)d_in[1];
    const float* W    = (const float*)d_in[2];
    const float* wa   = (const float*)d_in[3];
    const float* bias = (const float*)d_in[4];
    float* out = (float*)d_out;

    char* ws = (char*)d_ws;
    const size_t whB_bytes = (size_t)Nn * 64 * 2;   // 1.5 MB
    const size_t vec_bytes = (size_t)Nn * 4;        // 48 KB
    __bf16* whB = (__bf16*)ws;
    float*  src = (float*)(ws + whB_bytes);
    float*  dst = (float*)(ws + whB_bytes + vec_bytes);

    prep_kernel<<<Nn / 64, 256, 0, stream>>>(x, W, wa, whB, src, dst);
    attn_kernel<<<Nn / 16, 256, 0, stream>>>(mask, whB, src, dst, bias, out);
}

// Round 14
// 136.625 us; speedup vs baseline: 1.1031x; 1.0250x over previous
//
#include <hip/hip_runtime.h>
#include <hip/hip_bf16.h>
#include <cstddef>
#include <cstdint>

#define Nn 12288
#define LOG2E 1.44269504088896340736f
// LDS layout (ints): mask pair-bufs [2][16][516] = 16512 ; dst [2][256] at 16512
#define MROWI 516            // ints per mask row (2048 B + 16 pad)
#define MBUFI 8256           // ints per mask pair-buffer
#define DSTI  16512          // int offset of dst slots

typedef __bf16 bf16x8 __attribute__((ext_vector_type(8)));
typedef float  f32x4  __attribute__((ext_vector_type(4)));
typedef int    i32x4  __attribute__((ext_vector_type(4)));

__device__ __forceinline__ void gload_lds16_nt(const void* g, void* l) {
    __builtin_amdgcn_global_load_lds(
        (const __attribute__((address_space(1))) void*)g,
        (__attribute__((address_space(3))) void*)l, 16, 0, 2 /*nt*/);
}
__device__ __forceinline__ void gload_lds4(const void* g, void* l) {
    __builtin_amdgcn_global_load_lds(
        (const __attribute__((address_space(1))) void*)g,
        (__attribute__((address_space(3))) void*)l, 4, 0, 0);
}

// ---------------------------------------------------------------------------
// Kernel 1 (verified, unchanged): wh = x @ W; whB in MFMA-fragment order;
// src/dst prescaled by log2(e) for native exp2.
// ---------------------------------------------------------------------------
__global__ __launch_bounds__(256) void prep_kernel(
    const float* __restrict__ x, const float* __restrict__ W,
    const float* __restrict__ wa, __bf16* __restrict__ whB,
    float* __restrict__ src, float* __restrict__ dst)
{
    __shared__ float  Wl[64 * 64];
    __shared__ float  Xl[64 * 64];
    __shared__ __bf16 whl[64 * 72];
    int t = threadIdx.x;
    int R0 = blockIdx.x * 64;
    for (int i = t; i < 4096; i += 256) {
        Wl[i] = W[i];
        Xl[i] = x[(size_t)R0 * 64 + i];
    }
    __syncthreads();
    int c   = t & 63;
    int r16 = (t >> 6) * 16;
    float vals[16];
    #pragma unroll
    for (int k = 0; k < 16; ++k) vals[k] = 0.f;
    #pragma unroll 16
    for (int kk = 0; kk < 64; ++kk) {
        float wv = Wl[kk * 64 + c];
        #pragma unroll
        for (int k = 0; k < 16; ++k)
            vals[k] = fmaf(Xl[(r16 + k) * 64 + kk], wv, vals[k]);
    }
    #pragma unroll
    for (int k = 0; k < 16; ++k) whl[c * 72 + r16 + k] = (__bf16)vals[k];
    __syncthreads();
    if (t < 64) {
        float s = 0.f, d = 0.f;
        #pragma unroll 16
        for (int cc = 0; cc < 64; ++cc) {
            float v = (float)whl[cc * 72 + t];
            s = fmaf(v, wa[cc], s);
            d = fmaf(v, wa[64 + cc], d);
        }
        src[R0 + t] = s * LOG2E;
        dst[R0 + t] = d * LOG2E;
    }
    #pragma unroll
    for (int gg = 0; gg < 2; ++gg) {
        int gidx   = t * 2 + gg;
        int jc_loc = gidx >> 8;
        int q      = (gidx >> 6) & 3;
        int lane   = gidx & 63;
        int crow   = (lane & 15) + 16 * q;
        int jrow   = jc_loc * 32 + (lane >> 4) * 8;
        bf16x8 v = *(const bf16x8*)&whl[crow * 72 + jrow];
        int jc = blockIdx.x * 2 + jc_loc;
        *(bf16x8*)&whB[((size_t)(jc * 4 + q) * 64 + lane) * 8] = v;
    }
}

// ---------------------------------------------------------------------------
// Kernel 2: R13 structure (140.0 us verified) + per-block PHASE ROTATION of
// the j-sweep: pair p -> phi(p) = (p+g) % 24 (bijective; sums are order-
// independent). Decorrelates DRAM channel phase across blocks (row stride
// 48KB x 16 rows = 768KB aliases to the same channel set for every block).
// Mask, dst, whB all follow the rotated tile. Ledger unchanged: vmcnt(17).
// ---------------------------------------------------------------------------
__global__ __launch_bounds__(256) void attn_kernel(
    const int* __restrict__ mask, const __bf16* __restrict__ whB,
    const float* __restrict__ src, const float* __restrict__ dstv,
    const float* __restrict__ bias, float* __restrict__ out)
{
    __shared__ int lm[DSTI + 2 * 256];   // 68096 B

    int t    = threadIdx.x;
    int lane = t & 63;
    int wid  = t >> 6;
    int g    = blockIdx.x;
    int row  = lane & 15;
    int kg   = lane >> 4;
    int jl   = kg * 8;

    float srow = src[g * 16 + row];
    asm volatile("" :: "v"(srow));   // resolve before pipeline starts

    bf16x8 vones;
    #pragma unroll
    for (int e = 0; e < 8; ++e) vones[e] = (__bf16)1.0f;

    const char* mgb = (const char*)(mask + (size_t)g * 16 * Nn) + lane * 16;

    i32x4 bset[2][8];
    f32x4 acc0 = {0.f, 0.f, 0.f, 0.f}, acc1 = acc0, acc2 = acc0, acc3 = acc0;
    f32x4 accZ = acc0;

// phase rotation: pair P -> (P+g)%24 ; body B -> rotated tile index
#define PHI(P)  ((((P) + g) % 24))
#define RT(B)   (PHI((B) >> 1) * 2 + ((B) & 1))

// stage mask for (rotated) pair PR into buf SB: op k covers row k>>1, half k&1
#define MSTAGE(SB, PR)                                                        \
    do {                                                                      \
        int _ph = PHI(PR) * 2048;                                             \
        _Pragma("unroll")                                                     \
        for (int o = 0; o < 8; ++o) {                                         \
            int k    = wid * 8 + o;                                           \
            int rr   = k >> 1;                                                \
            int half = k & 1;                                                 \
            gload_lds16_nt(mgb + (size_t)rr * (Nn * 4) + _ph + half * 1024,   \
                           (char*)lm + (SB) * (MBUFI * 4) + rr * (MROWI * 4) +\
                               half * 1024);                                  \
        }                                                                     \
    } while (0)

#define DSTAGE(PS, TT)                                                        \
    gload_lds4(dstv + RT(TT) * 256 + wid * 64 + lane,                         \
               (char*)lm + DSTI * 4 + (PS) * 1024 + wid * 256)

#define BLOAD(PS, TT)                                                         \
    do {                                                                      \
        const char* _b0 = (const char*)whB +                                  \
                          ((size_t)(RT(TT) * 8 + wid * 2)) * 4096 +           \
                          (size_t)lane * 16;                                  \
        const char* _b1 = _b0 + 4096;                                         \
        asm volatile("global_load_dwordx4 %0, %1, off"                        \
                     : "=v"(bset[PS][0]) : "v"(_b0));                         \
        asm volatile("global_load_dwordx4 %0, %1, off offset:1024"            \
                     : "=v"(bset[PS][1]) : "v"(_b0));                         \
        asm volatile("global_load_dwordx4 %0, %1, off offset:2048"            \
                     : "=v"(bset[PS][2]) : "v"(_b0));                         \
        asm volatile("global_load_dwordx4 %0, %1, off offset:3072"            \
                     : "=v"(bset[PS][3]) : "v"(_b0));                         \
        asm volatile("global_load_dwordx4 %0, %1, off"                        \
                     : "=v"(bset[PS][4]) : "v"(_b1));                         \
        asm volatile("global_load_dwordx4 %0, %1, off offset:1024"            \
                     : "=v"(bset[PS][5]) : "v"(_b1));                         \
        asm volatile("global_load_dwordx4 %0, %1, off offset:2048"            \
                     : "=v"(bset[PS][6]) : "v"(_b1));                         \
        asm volatile("global_load_dwordx4 %0, %1, off offset:3072"            \
                     : "=v"(bset[PS][7]) : "v"(_b1));                         \
    } while (0)

#define COMPUTE(MB, H, PS)                                                    \
    do {                                                                      \
        const int*   mb = &lm[(MB) * MBUFI + row * MROWI + (H) * 256 +        \
                              wid * 64];                                      \
        const float* db = (const float*)&lm[DSTI + (PS) * 256 + wid * 64];    \
        _Pragma("unroll")                                                     \
        for (int cc = 0; cc < 2; ++cc) {                                      \
            i32x4 m0 = *(const i32x4*)(mb + cc * 32 + jl);                    \
            i32x4 m1 = *(const i32x4*)(mb + cc * 32 + jl + 4);                \
            f32x4 d0 = *(const f32x4*)(db + cc * 32 + jl);                    \
            f32x4 d1 = *(const f32x4*)(db + cc * 32 + jl + 4);                \
            bf16x8 pa;                                                        \
            _Pragma("unroll")                                                 \
            for (int e = 0; e < 4; ++e) {                                     \
                float f0 = srow + d0[e];                                      \
                f0 = fmaxf(f0, 0.01f * f0);                                   \
                float w0 = __builtin_amdgcn_exp2f(f0);                        \
                w0 = (m0[e] > 0) ? w0 : 0.f;                                  \
                pa[e] = (__bf16)w0;                                           \
                float f1 = srow + d1[e];                                      \
                f1 = fmaxf(f1, 0.01f * f1);                                   \
                float w1 = __builtin_amdgcn_exp2f(f1);                        \
                w1 = (m1[e] > 0) ? w1 : 0.f;                                  \
                pa[4 + e] = (__bf16)w1;                                       \
            }                                                                 \
            acc0 = __builtin_amdgcn_mfma_f32_16x16x32_bf16(                   \
                pa, __builtin_bit_cast(bf16x8, bset[PS][cc * 4 + 0]), acc0, 0, 0, 0); \
            acc1 = __builtin_amdgcn_mfma_f32_16x16x32_bf16(                   \
                pa, __builtin_bit_cast(bf16x8, bset[PS][cc * 4 + 1]), acc1, 0, 0, 0); \
            acc2 = __builtin_amdgcn_mfma_f32_16x16x32_bf16(                   \
                pa, __builtin_bit_cast(bf16x8, bset[PS][cc * 4 + 2]), acc2, 0, 0, 0); \
            acc3 = __builtin_amdgcn_mfma_f32_16x16x32_bf16(                   \
                pa, __builtin_bit_cast(bf16x8, bset[PS][cc * 4 + 3]), acc3, 0, 0, 0); \
            accZ = __builtin_amdgcn_mfma_f32_16x16x32_bf16(                   \
                pa, vones, accZ, 0, 0, 0);                                    \
        }                                                                     \
    } while (0)

#define WAITBAR(N)                                                            \
    do {                                                                      \
        asm volatile("s_waitcnt vmcnt(" #N ")" ::: "memory");                 \
        __builtin_amdgcn_sched_barrier(0);                                    \
        __builtin_amdgcn_s_barrier();                                         \
        __builtin_amdgcn_sched_barrier(0);                                    \
    } while (0)

// one pair = even body (stages next pair's mask) + odd body
#define PAIR_BODY(MB, SB)                                                     \
    do {                                                                      \
        BLOAD(1, tt + 1);                                                     \
        DSTAGE(1, tt + 1);                                                    \
        MSTAGE(SB, pr + 1);                                                   \
        WAITBAR(17);                                                          \
        COMPUTE(MB, 0, 0);                                                    \
        __builtin_amdgcn_s_barrier();                                         \
        ++tt;                                                                 \
        BLOAD(0, tt + 1);                                                     \
        DSTAGE(0, tt + 1);                                                    \
        WAITBAR(17);                                                          \
        COMPUTE(MB, 1, 1);                                                    \
        __builtin_amdgcn_s_barrier();                                         \
        ++tt;                                                                 \
        ++pr;                                                                 \
    } while (0)

    int tt = 0, pr = 0;
    // prologue: rotated pair phi(0) -> buf 0, dst/B of rotated tile RT(0)
    MSTAGE(0, 0);
    DSTAGE(0, 0);
    BLOAD(0, 0);
    __builtin_amdgcn_sched_barrier(0);

    for (int it = 0; it < 11; ++it) {   // pairs 0..21
        PAIR_BODY(0, 1);
        PAIR_BODY(1, 0);
    }
    PAIR_BODY(0, 1);                    // pair 22 (stages pair 23 -> buf 1)

    // pair 23 (MB=1): even body 46
    BLOAD(1, tt + 1);
    DSTAGE(1, tt + 1);
    WAITBAR(9);
    COMPUTE(1, 0, 0);
    __builtin_amdgcn_s_barrier();
    // odd body 47
    WAITBAR(0);
    COMPUTE(1, 1, 1);

#undef PAIR_BODY
#undef WAITBAR
#undef COMPUTE
#undef BLOAD
#undef DSTAGE
#undef MSTAGE
#undef RT
#undef PHI

    // block reduce: 4 wave partials -> (16 x 64) tile, normalize, + bias
    __syncthreads();
    float* red  = (float*)lm;          // [4][1024]
    float* redz = red + 4096;          // [4][16]
    #pragma unroll
    for (int r = 0; r < 4; ++r) {
        int orow = kg * 4 + r;         // C/D: row = 4*(lane>>4)+reg, col = lane&15
        red[wid * 1024 + orow * 64 + row]      = acc0[r];
        red[wid * 1024 + orow * 64 + row + 16] = acc1[r];
        red[wid * 1024 + orow * 64 + row + 32] = acc2[r];
        red[wid * 1024 + orow * 64 + row + 48] = acc3[r];
    }
    if (row == 0) {
        #pragma unroll
        for (int r = 0; r < 4; ++r) redz[wid * 16 + kg * 4 + r] = accZ[r];
    }
    __syncthreads();
    #pragma unroll
    for (int k = 0; k < 4; ++k) {
        int idx = k * 256 + t;
        int i   = idx >> 6;
        float sv = red[idx] + red[1024 + idx] + red[2048 + idx] + red[3072 + idx];
        float z  = redz[i] + redz[16 + i] + redz[32 + i] + redz[48 + i];
        z = (z != 0.f) ? z : 1.f;
        out[(size_t)g * 1024 + idx] = sv / z + bias[idx & 63];
    }
}

extern "C" void kernel_launch(void* const* d_in, const int* in_sizes, int n_in,
                              void* d_out, int out_size, void* d_ws, size_t ws_size,
                              hipStream_t stream) {
    const float* x    = (const float*)d_in[0];
    const int*   mask = (const int*)d_in[1];
    const float* W    = (const float*)d_in[2];
    const float* wa   = (const float*)d_in[3];
    const float* bias = (const float*)d_in[4];
    float* out = (float*)d_out;

    char* ws = (char*)d_ws;
    const size_t whB_bytes = (size_t)Nn * 64 * 2;   // 1.5 MB
    const size_t vec_bytes = (size_t)Nn * 4;        // 48 KB
    __bf16* whB = (__bf16*)ws;
    float*  src = (float*)(ws + whB_bytes);
    float*  dst = (float*)(ws + whB_bytes + vec_bytes);

    prep_kernel<<<Nn / 64, 256, 0, stream>>>(x, W, wa, whB, src, dst);
    attn_kernel<<<Nn / 16, 256, 0, stream>>>(mask, whB, src, dst, bias, out);
}